// Round 8
// baseline (105.418 us; speedup 1.0000x reference)
//
#include <hip/hip_runtime.h>
#include <math.h>

#define NN 2048
#define EE 1024

typedef unsigned long long ull;

// ---------------------------------------------------------------------------
// D1 k_scan: three independent jobs by block range (grid = 1024).
//   [0,512)    rfill : wave per node row -> elist[n][128], cnt[n], dn[n]
//   [512,768)  cscan : wave per edge col -> clist[e][192], ccnt[e], de[e]
//   [768,1024) npb   : node projection npb = x @ W1[:, :64]^T + b1 (8 rows/blk)
// ---------------------------------------------------------------------------
__global__ void k_scan(const float* __restrict__ H, const float* __restrict__ x,
                       const float* __restrict__ W1, const float* __restrict__ b1,
                       unsigned short* __restrict__ elist, int* __restrict__ cnt,
                       float* __restrict__ dn,
                       unsigned short* __restrict__ clist, int* __restrict__ ccnt,
                       float* __restrict__ de,
                       float* __restrict__ npb) {
  __shared__ __align__(16) float smem[64 * 129 + 8 * 64];
  int bid = blockIdx.x, t = threadIdx.x;
  if (bid < 512) {
    // ---- rfill (coalesced row scans)
    int n = bid * 4 + (t >> 6), lane = t & 63;
    const float* row = H + (size_t)n * EE;
    int count = 0;
    for (int i = 0; i < EE; i += 64) {
      float hv = row[i + lane];
      ull m = __ballot(hv != 0.f);
      int pos = count + __popcll(m & ((1ull << lane) - 1ull));
      if (hv != 0.f && pos < 128) elist[n * 128 + pos] = (unsigned short)(i + lane);
      count += __popcll(m);
    }
    if (lane == 0) {
      cnt[n] = count;
      dn[n] = count ? rsqrtf((float)count) : 0.f;
    }
  } else if (bid < 768) {
    // ---- cscan (column scans; lines shared 4-ways within block via L1/L2)
    int e = (bid - 512) * 4 + (t >> 6), lane = t & 63;
    int count = 0;
    for (int i = 0; i < NN; i += 64) {
      float hv = H[(size_t)(i + lane) * EE + e];
      ull m = __ballot(hv != 0.f);
      int pos = count + __popcll(m & ((1ull << lane) - 1ull));
      if (hv != 0.f && pos < 192) clist[e * 192 + pos] = (unsigned short)(i + lane);
      count += __popcll(m);
    }
    if (lane == 0) {
      ccnt[e] = count;
      de[e] = count ? 1.f / (float)count : 0.f;
    }
  } else {
    // ---- npb: 8 rows x 128 h per block; W1 node-half transposed in LDS
    float* Wt = smem;              // Wt[d*129 + h], conflict-free scalar reads
    float* xl = smem + 64 * 129;   // xl[8][64]
    int b = bid - 768;
    int r0 = b * 8;
    #pragma unroll
    for (int p = 0; p < 32; ++p) {
      int j = t + p * 256;         // j < 8192: h = j>>6 row of W1, d = j&63
      int h = j >> 6, d = j & 63;
      Wt[d * 129 + h] = W1[h * 128 + d];
    }
    {
      int r = t >> 6, d = t & 63;
      xl[(r + 0) * 64 + d] = x[(size_t)(r0 + r) * 64 + d];
      xl[(r + 4) * 64 + d] = x[(size_t)(r0 + r + 4) * 64 + d];
    }
    __syncthreads();
    #pragma unroll
    for (int k = 0; k < 4; ++k) {
      int idx = t + k * 256;       // 1024 outputs: row = idx>>7, h = idx&127
      int row = idx >> 7, h = idx & 127;
      float acc = b1[h];
      #pragma unroll 8
      for (int d = 0; d < 64; ++d)
        acc += xl[row * 64 + d] * Wt[d * 129 + h];
      npb[(size_t)(r0 + row) * 128 + h] = acc;
    }
  }
}

// ---------------------------------------------------------------------------
// D2 k_edge: ef gather + edge projection fused.  4 edges/block (grid = 256).
//   ef[e][d] = sum_{n in col(e)} x[n][d]      (wave per edge, coalesced rows)
//   epb[e][h] = ef[e] . W1[h][64:128]          (no bias)
// ---------------------------------------------------------------------------
__global__ void k_edge(const unsigned short* __restrict__ clist,
                       const int* __restrict__ ccnt,
                       const float* __restrict__ x, const float* __restrict__ W1,
                       float* __restrict__ epb) {
  __shared__ __align__(16) float smem[64 * 129 + 4 * 64];
  float* Wt = smem;               // Wt[d*129 + h] = W1[h][64+d]
  float* efl = smem + 64 * 129;   // efl[4][64]
  int t = threadIdx.x, wv = t >> 6, lane = t & 63;
  int e0 = blockIdx.x * 4;
  #pragma unroll
  for (int p = 0; p < 32; ++p) {
    int j = t + p * 256;
    int h = j >> 6, d = j & 63;
    Wt[d * 129 + h] = W1[h * 128 + 64 + d];
  }
  {
    int e = e0 + wv;
    int c = min(ccnt[e], 192);
    float acc = 0.f;
    for (int j = 0; j < c; ++j) {
      int n = clist[e * 192 + j];
      acc += x[(size_t)n * 64 + lane];
    }
    efl[wv * 64 + lane] = acc;
  }
  __syncthreads();
  #pragma unroll
  for (int k = 0; k < 2; ++k) {
    int idx = t + k * 256;         // 512 outputs: el = idx>>7, h = idx&127
    int el = idx >> 7, h = idx & 127;
    float acc = 0.f;
    #pragma unroll 8
    for (int d = 0; d < 64; ++d)
      acc += efl[el * 64 + d] * Wt[d * 129 + h];
    epb[(size_t)(e0 + el) * 128 + h] = acc;
  }
}

// ---------------------------------------------------------------------------
// D3 k_pscore: scores in BOTH orderings; 4 lanes per slot.
//   slots [0, NN*128)       : sval_r[n][j] = sigmoid(score)
//   slots [NN*128, +EE*192) : sval_c[e][j] = sigmoid(score) * dn[n]
// ---------------------------------------------------------------------------
__global__ void k_pscore(const float* __restrict__ npb, const float* __restrict__ epb,
                         const float* __restrict__ W2, const float* __restrict__ b2,
                         const int* __restrict__ cnt, const unsigned short* __restrict__ elist,
                         const int* __restrict__ ccnt, const unsigned short* __restrict__ clist,
                         const float* __restrict__ dn,
                         float* __restrict__ sval_r, float* __restrict__ sval_c) {
  int gid = blockIdx.x * blockDim.x + threadIdx.x;
  int sub = gid & 3;
  int slot = gid >> 2;
  int n, e;
  float scale;
  float* dst;
  if (slot < NN * 128) {
    n = slot >> 7;
    int j = slot & 127;
    if (j >= min(cnt[n], 128)) return;
    e = elist[slot];
    scale = 1.f;
    dst = sval_r + slot;
  } else {
    int cs = slot - NN * 128;
    e = cs / 192;
    int j = cs - e * 192;
    if (j >= min(ccnt[e], 192)) return;
    n = clist[cs];
    scale = dn[n];
    dst = sval_c + cs;
  }
  const float* npr = npb + (size_t)n * 128;
  const float* epr = epb + (size_t)e * 128;
  float acc = 0.f;
  #pragma unroll
  for (int q = 0; q < 8; ++q) {
    float4 a = *(const float4*)&npr[q * 16 + sub * 4];
    float4 c = *(const float4*)&epr[q * 16 + sub * 4];
    float4 w2 = *(const float4*)&W2[q * 16 + sub * 4];
    acc += fmaxf(a.x + c.x, 0.f) * w2.x + fmaxf(a.y + c.y, 0.f) * w2.y
         + fmaxf(a.z + c.z, 0.f) * w2.z + fmaxf(a.w + c.w, 0.f) * w2.w;
  }
  acc += __shfl_xor(acc, 1, 64);
  acc += __shfl_xor(acc, 2, 64);
  if (sub == 0)
    *dst = scale / (1.f + __expf(-(acc + b2[0])));
}

// ---------------------------------------------------------------------------
// D4 k_w: w[e][d] = de[e] * sum_j sval_c[e][j] * x[n_j][d]
// one block (4 waves) per edge; j strided by wave; LDS combine.
// ---------------------------------------------------------------------------
__global__ void k_w(const unsigned short* __restrict__ clist, const int* __restrict__ ccnt,
                    const float* __restrict__ de, const float* __restrict__ sval_c,
                    const float* __restrict__ x, float* __restrict__ w) {
  __shared__ float psum[4][64];
  int t = threadIdx.x, wv = t >> 6, lane = t & 63;
  int e = blockIdx.x;
  int c = min(ccnt[e], 192);
  float acc = 0.f;
  for (int j = wv; j < c; j += 4) {
    int n = clist[e * 192 + j];
    acc += sval_c[e * 192 + j] * x[(size_t)n * 64 + lane];
  }
  psum[wv][lane] = acc;
  __syncthreads();
  if (wv == 0)
    w[(size_t)e * 64 + lane] =
        de[e] * (psum[0][lane] + psum[1][lane] + psum[2][lane] + psum[3][lane]);
}

// ---------------------------------------------------------------------------
// D5 k_zout: 4 nodes per block (grid = 512).
//   z[d] = dn[n] * sum_j sval_r[n][j] * w[e_j][d]   (wave per node)
//   out[n][o] = z . Wl[o] + bl[o]                    (fused final linear)
// ---------------------------------------------------------------------------
__global__ void k_zout(const unsigned short* __restrict__ elist, const int* __restrict__ cnt,
                       const float* __restrict__ dn, const float* __restrict__ sval_r,
                       const float* __restrict__ w, const float* __restrict__ Wlg,
                       const float* __restrict__ bl, float* __restrict__ out) {
  __shared__ float Wlds[64 * 65];
  __shared__ float zl[4][64];
  int t = threadIdx.x, wv = t >> 6, lane = t & 63;
  int n0 = blockIdx.x * 4;
  for (int j = t; j < 4096; j += 256)
    Wlds[(j >> 6) * 65 + (j & 63)] = Wlg[j];
  {
    int n = n0 + wv;
    int c = min(cnt[n], 128);
    float acc = 0.f;
    for (int j = 0; j < c; ++j) {
      int e = elist[n * 128 + j];
      acc += sval_r[n * 128 + j] * w[(size_t)e * 64 + lane];
    }
    zl[wv][lane] = dn[n] * acc;
  }
  __syncthreads();
  {
    int node = t >> 6, o = t & 63;
    float po = bl[o];
    #pragma unroll 8
    for (int d = 0; d < 64; ++d)
      po += zl[node][d] * Wlds[o * 65 + d];
    out[(size_t)(n0 + node) * 64 + o] = po;
  }
}

extern "C" void kernel_launch(void* const* d_in, const int* in_sizes, int n_in,
                              void* d_out, int out_size, void* d_ws, size_t ws_size,
                              hipStream_t stream) {
  const float* x  = (const float*)d_in[0];
  const float* H  = (const float*)d_in[1];
  const float* W1 = (const float*)d_in[2];
  const float* b1 = (const float*)d_in[3];
  const float* W2 = (const float*)d_in[4];
  const float* b2 = (const float*)d_in[5];
  const float* Wl = (const float*)d_in[6];
  const float* bl = (const float*)d_in[7];
  float* out = (float*)d_out;

  char* wsb = (char*)d_ws;
  float* dn     = (float*)wsb;  wsb += NN * 4;
  float* de     = (float*)wsb;  wsb += EE * 4;
  int*   cnt    = (int*)wsb;    wsb += NN * 4;
  int*   ccnt   = (int*)wsb;    wsb += EE * 4;
  float* npb    = (float*)wsb;  wsb += (size_t)NN * 128 * 4;
  float* epb    = (float*)wsb;  wsb += (size_t)EE * 128 * 4;
  float* sval_r = (float*)wsb;  wsb += (size_t)NN * 128 * 4;
  float* sval_c = (float*)wsb;  wsb += (size_t)EE * 192 * 4;
  float* w      = (float*)wsb;  wsb += (size_t)EE * 64 * 4;
  unsigned short* elist = (unsigned short*)wsb; wsb += (size_t)NN * 128 * 2;
  unsigned short* clist = (unsigned short*)wsb; wsb += (size_t)EE * 192 * 2;

  // D1: structure + degrees + node projection
  hipLaunchKernelGGL(k_scan, dim3(1024), dim3(256), 0, stream,
                     H, x, W1, b1, elist, cnt, dn, clist, ccnt, de, npb);
  // D2: ef gather + edge projection (dense GEMM + part roundtrip eliminated)
  hipLaunchKernelGGL(k_edge, dim3(EE / 4), dim3(256), 0, stream,
                     clist, ccnt, x, W1, epb);
  // D3: sparse attention scores in both orderings
  hipLaunchKernelGGL(k_pscore, dim3((NN * 128 + EE * 192) * 4 / 256), dim3(256), 0, stream,
                     npb, epb, W2, b2, cnt, elist, ccnt, clist, dn, sval_r, sval_c);
  // D4: w = de * (M^T @ (dn*x))  via CSC lists
  hipLaunchKernelGGL(k_w, dim3(EE), dim3(256), 0, stream,
                     clist, ccnt, de, sval_c, x, w);
  // D5: z = dn * (M @ w); out = z @ Wl^T + bl  via CSR lists
  hipLaunchKernelGGL(k_zout, dim3(NN / 4), dim3(256), 0, stream,
                     elist, cnt, dn, sval_r, w, Wl, bl, out);
}

// Round 9
// 86.317 us; speedup vs baseline: 1.2213x; 1.2213x over previous
//
#include <hip/hip_runtime.h>
#include <math.h>

#define NN 2048
#define EE 1024

typedef unsigned long long ull;

// ---------------------------------------------------------------------------
// D1 k_scan: three independent jobs by block range (grid = 1024).
//   [0,512)    rfill : wave per node row -> elist[n][128], cnt[n], dn[n]
//   [512,768)  cscan : wave per edge col -> clist[e][192], ccnt[e], de[e]
//   [768,1024) npb   : node projection npb = x @ W1[:, :64]^T + b1 (8 rows/blk)
// ---------------------------------------------------------------------------
__global__ void k_scan(const float* __restrict__ H, const float* __restrict__ x,
                       const float* __restrict__ W1, const float* __restrict__ b1,
                       unsigned short* __restrict__ elist, int* __restrict__ cnt,
                       float* __restrict__ dn,
                       unsigned short* __restrict__ clist, int* __restrict__ ccnt,
                       float* __restrict__ de,
                       float* __restrict__ npb) {
  __shared__ __align__(16) float smem[64 * 129 + 8 * 64];
  int bid = blockIdx.x, t = threadIdx.x;
  if (bid < 512) {
    // ---- rfill (coalesced row scans)
    int n = bid * 4 + (t >> 6), lane = t & 63;
    const float* row = H + (size_t)n * EE;
    int count = 0;
    for (int i = 0; i < EE; i += 64) {
      float hv = row[i + lane];
      ull m = __ballot(hv != 0.f);
      int pos = count + __popcll(m & ((1ull << lane) - 1ull));
      if (hv != 0.f && pos < 128) elist[n * 128 + pos] = (unsigned short)(i + lane);
      count += __popcll(m);
    }
    if (lane == 0) {
      cnt[n] = count;
      dn[n] = count ? rsqrtf((float)count) : 0.f;
    }
  } else if (bid < 768) {
    // ---- cscan (column scans; lines shared 4-ways within block via L1/L2)
    int e = (bid - 512) * 4 + (t >> 6), lane = t & 63;
    int count = 0;
    for (int i = 0; i < NN; i += 64) {
      float hv = H[(size_t)(i + lane) * EE + e];
      ull m = __ballot(hv != 0.f);
      int pos = count + __popcll(m & ((1ull << lane) - 1ull));
      if (hv != 0.f && pos < 192) clist[e * 192 + pos] = (unsigned short)(i + lane);
      count += __popcll(m);
    }
    if (lane == 0) {
      ccnt[e] = count;
      de[e] = count ? 1.f / (float)count : 0.f;
    }
  } else {
    // ---- npb: 8 rows x 128 h per block; W1 node-half transposed in LDS
    float* Wt = smem;              // Wt[d*129 + h], conflict-free scalar reads
    float* xl = smem + 64 * 129;   // xl[8][64]
    int b = bid - 768;
    int r0 = b * 8;
    #pragma unroll
    for (int p = 0; p < 32; ++p) {
      int j = t + p * 256;
      int h = j >> 6, d = j & 63;
      Wt[d * 129 + h] = W1[h * 128 + d];
    }
    {
      int r = t >> 6, d = t & 63;
      xl[(r + 0) * 64 + d] = x[(size_t)(r0 + r) * 64 + d];
      xl[(r + 4) * 64 + d] = x[(size_t)(r0 + r + 4) * 64 + d];
    }
    __syncthreads();
    #pragma unroll
    for (int k = 0; k < 4; ++k) {
      int idx = t + k * 256;
      int row = idx >> 7, h = idx & 127;
      float acc = b1[h];
      #pragma unroll 8
      for (int d = 0; d < 64; ++d)
        acc += xl[row * 64 + d] * Wt[d * 129 + h];
      npb[(size_t)(r0 + row) * 128 + h] = acc;
    }
  }
}

// ---------------------------------------------------------------------------
// D2 k_ef: one block per edge (grid = EE).  LESSON(R8): sparse gathers need
// >=4K waves and <=~30 serial iters -- wave-per-edge serial loops are 35us+.
//   gather: ef[d] = sum_{n in col(e)} x[n][d], j strided across 4 waves
//   project: epb[e][h] = ef . W1[h][64:128]  (W1 read from global, L1-resident)
// ---------------------------------------------------------------------------
__global__ void k_ef(const unsigned short* __restrict__ clist,
                     const int* __restrict__ ccnt,
                     const float* __restrict__ x, const float* __restrict__ W1,
                     float* __restrict__ epb) {
  __shared__ float psum[4][64];
  __shared__ float efl[64];
  int t = threadIdx.x, wv = t >> 6, lane = t & 63;
  int e = blockIdx.x;
  int c = min(ccnt[e], 192);
  float acc = 0.f;
  for (int j = wv; j < c; j += 4) {
    int n = clist[e * 192 + j];
    acc += x[(size_t)n * 64 + lane];
  }
  psum[wv][lane] = acc;
  __syncthreads();
  if (wv == 0)
    efl[lane] = psum[0][lane] + psum[1][lane] + psum[2][lane] + psum[3][lane];
  __syncthreads();
  if (t < 128) {
    int h = t;
    const float* wr = W1 + h * 128 + 64;
    float a = 0.f;
    #pragma unroll
    for (int q = 0; q < 16; ++q) {
      float4 wv4 = *(const float4*)&wr[q * 4];
      a += efl[q * 4 + 0] * wv4.x + efl[q * 4 + 1] * wv4.y
         + efl[q * 4 + 2] * wv4.z + efl[q * 4 + 3] * wv4.w;
    }
    epb[(size_t)e * 128 + h] = a;
  }
}

// ---------------------------------------------------------------------------
// D3 k_pscore: scores in BOTH orderings; 4 lanes per slot.
//   slots [0, NN*128)       : sval_r[n][j] = sigmoid(score)
//   slots [NN*128, +EE*192) : sval_c[e][j] = sigmoid(score) * dn[n]
// ---------------------------------------------------------------------------
__global__ void k_pscore(const float* __restrict__ npb, const float* __restrict__ epb,
                         const float* __restrict__ W2, const float* __restrict__ b2,
                         const int* __restrict__ cnt, const unsigned short* __restrict__ elist,
                         const int* __restrict__ ccnt, const unsigned short* __restrict__ clist,
                         const float* __restrict__ dn,
                         float* __restrict__ sval_r, float* __restrict__ sval_c) {
  int gid = blockIdx.x * blockDim.x + threadIdx.x;
  int sub = gid & 3;
  int slot = gid >> 2;
  int n, e;
  float scale;
  float* dst;
  if (slot < NN * 128) {
    n = slot >> 7;
    int j = slot & 127;
    if (j >= min(cnt[n], 128)) return;
    e = elist[slot];
    scale = 1.f;
    dst = sval_r + slot;
  } else {
    int cs = slot - NN * 128;
    e = cs / 192;
    int j = cs - e * 192;
    if (j >= min(ccnt[e], 192)) return;
    n = clist[cs];
    scale = dn[n];
    dst = sval_c + cs;
  }
  const float* npr = npb + (size_t)n * 128;
  const float* epr = epb + (size_t)e * 128;
  float acc = 0.f;
  #pragma unroll
  for (int q = 0; q < 8; ++q) {
    float4 a = *(const float4*)&npr[q * 16 + sub * 4];
    float4 c = *(const float4*)&epr[q * 16 + sub * 4];
    float4 w2 = *(const float4*)&W2[q * 16 + sub * 4];
    acc += fmaxf(a.x + c.x, 0.f) * w2.x + fmaxf(a.y + c.y, 0.f) * w2.y
         + fmaxf(a.z + c.z, 0.f) * w2.z + fmaxf(a.w + c.w, 0.f) * w2.w;
  }
  acc += __shfl_xor(acc, 1, 64);
  acc += __shfl_xor(acc, 2, 64);
  if (sub == 0)
    *dst = scale / (1.f + __expf(-(acc + b2[0])));
}

// ---------------------------------------------------------------------------
// D4 k_w: w[e][d] = de[e] * sum_j sval_c[e][j] * x[n_j][d]
// one block (4 waves) per edge; j strided by wave; LDS combine.
// ---------------------------------------------------------------------------
__global__ void k_w(const unsigned short* __restrict__ clist, const int* __restrict__ ccnt,
                    const float* __restrict__ de, const float* __restrict__ sval_c,
                    const float* __restrict__ x, float* __restrict__ w) {
  __shared__ float psum[4][64];
  int t = threadIdx.x, wv = t >> 6, lane = t & 63;
  int e = blockIdx.x;
  int c = min(ccnt[e], 192);
  float acc = 0.f;
  for (int j = wv; j < c; j += 4) {
    int n = clist[e * 192 + j];
    acc += sval_c[e * 192 + j] * x[(size_t)n * 64 + lane];
  }
  psum[wv][lane] = acc;
  __syncthreads();
  if (wv == 0)
    w[(size_t)e * 64 + lane] =
        de[e] * (psum[0][lane] + psum[1][lane] + psum[2][lane] + psum[3][lane]);
}

// ---------------------------------------------------------------------------
// D5 k_zout: 4 nodes per block (grid = 512).
//   z[d] = dn[n] * sum_j sval_r[n][j] * w[e_j][d]   (wave per node, ~51 iters)
//   out[n][o] = z . Wl[o] + bl[o]                    (fused final linear)
// ---------------------------------------------------------------------------
__global__ void k_zout(const unsigned short* __restrict__ elist, const int* __restrict__ cnt,
                       const float* __restrict__ dn, const float* __restrict__ sval_r,
                       const float* __restrict__ w, const float* __restrict__ Wlg,
                       const float* __restrict__ bl, float* __restrict__ out) {
  __shared__ float Wlds[64 * 65];
  __shared__ float zl[4][64];
  int t = threadIdx.x, wv = t >> 6, lane = t & 63;
  int n0 = blockIdx.x * 4;
  for (int j = t; j < 4096; j += 256)
    Wlds[(j >> 6) * 65 + (j & 63)] = Wlg[j];
  {
    int n = n0 + wv;
    int c = min(cnt[n], 128);
    float acc = 0.f;
    for (int j = 0; j < c; ++j) {
      int e = elist[n * 128 + j];
      acc += sval_r[n * 128 + j] * w[(size_t)e * 64 + lane];
    }
    zl[wv][lane] = dn[n] * acc;
  }
  __syncthreads();
  {
    int node = t >> 6, o = t & 63;
    float po = bl[o];
    #pragma unroll 8
    for (int d = 0; d < 64; ++d)
      po += zl[node][d] * Wlds[o * 65 + d];
    out[(size_t)(n0 + node) * 64 + o] = po;
  }
}

extern "C" void kernel_launch(void* const* d_in, const int* in_sizes, int n_in,
                              void* d_out, int out_size, void* d_ws, size_t ws_size,
                              hipStream_t stream) {
  const float* x  = (const float*)d_in[0];
  const float* H  = (const float*)d_in[1];
  const float* W1 = (const float*)d_in[2];
  const float* b1 = (const float*)d_in[3];
  const float* W2 = (const float*)d_in[4];
  const float* b2 = (const float*)d_in[5];
  const float* Wl = (const float*)d_in[6];
  const float* bl = (const float*)d_in[7];
  float* out = (float*)d_out;

  char* wsb = (char*)d_ws;
  float* dn     = (float*)wsb;  wsb += NN * 4;
  float* de     = (float*)wsb;  wsb += EE * 4;
  int*   cnt    = (int*)wsb;    wsb += NN * 4;
  int*   ccnt   = (int*)wsb;    wsb += EE * 4;
  float* npb    = (float*)wsb;  wsb += (size_t)NN * 128 * 4;
  float* epb    = (float*)wsb;  wsb += (size_t)EE * 128 * 4;
  float* sval_r = (float*)wsb;  wsb += (size_t)NN * 128 * 4;
  float* sval_c = (float*)wsb;  wsb += (size_t)EE * 192 * 4;
  float* w      = (float*)wsb;  wsb += (size_t)EE * 64 * 4;
  unsigned short* elist = (unsigned short*)wsb; wsb += (size_t)NN * 128 * 2;
  unsigned short* clist = (unsigned short*)wsb; wsb += (size_t)EE * 192 * 2;

  // D1: structure + degrees + node projection
  hipLaunchKernelGGL(k_scan, dim3(1024), dim3(256), 0, stream,
                     H, x, W1, b1, elist, cnt, dn, clist, ccnt, de, npb);
  // D2: ef gather (4-wave strided) + edge projection, block per edge
  hipLaunchKernelGGL(k_ef, dim3(EE), dim3(256), 0, stream,
                     clist, ccnt, x, W1, epb);
  // D3: sparse attention scores in both orderings
  hipLaunchKernelGGL(k_pscore, dim3((NN * 128 + EE * 192) * 4 / 256), dim3(256), 0, stream,
                     npb, epb, W2, b2, cnt, elist, ccnt, clist, dn, sval_r, sval_c);
  // D4: w = de * (M^T @ (dn*x))  via CSC lists
  hipLaunchKernelGGL(k_w, dim3(EE), dim3(256), 0, stream,
                     clist, ccnt, de, sval_c, x, w);
  // D5: z = dn * (M @ w); out = z @ Wl^T + bl  via CSR lists
  hipLaunchKernelGGL(k_zout, dim3(NN / 4), dim3(256), 0, stream,
                     elist, cnt, dn, sval_r, w, Wl, bl, out);
}

// Round 10
// 71.982 us; speedup vs baseline: 1.4645x; 1.1991x over previous
//
#include <hip/hip_runtime.h>
#include <math.h>

#define NN 2048
#define EE 1024

typedef unsigned long long ull;

// ---------------------------------------------------------------------------
// D1 k_scan (grid 1792): three jobs by block range.
//   [0,1024)     cscan : block per edge column; 4 waves x 512-row segments,
//                        single pass, entries buffered in LDS -> clist/ccnt/de
//   [1024,1536)  rfill : wave per node row -> elist[n][128], cnt[n], dn[n]
//   [1536,1792)  npb   : node projection npb = x @ W1[:, :64]^T + b1
// LESSON(R8): sparse/serial loops need >=4K waves and <=~30 iters each.
// ---------------------------------------------------------------------------
__global__ void k_scan(const float* __restrict__ H, const float* __restrict__ x,
                       const float* __restrict__ W1, const float* __restrict__ b1,
                       unsigned short* __restrict__ elist, int* __restrict__ cnt,
                       float* __restrict__ dn,
                       unsigned short* __restrict__ clist, int* __restrict__ ccnt,
                       float* __restrict__ de,
                       float* __restrict__ npb) {
  __shared__ __align__(16) float smem[64 * 129 + 8 * 64];
  __shared__ unsigned short cbuf[4][128];
  __shared__ int csh[4];
  int bid = blockIdx.x, t = threadIdx.x, wv = t >> 6, lane = t & 63;
  if (bid < 1024) {
    // ---- cscan: one column per block; wave wv scans rows [wv*512, wv*512+512)
    int e = bid;
    int count = 0;
    int r0 = wv * 512;
    #pragma unroll
    for (int i = 0; i < 8; ++i) {
      int r = r0 + i * 64 + lane;
      float hv = H[(size_t)r * EE + e];
      ull m = __ballot(hv != 0.f);
      int pos = count + __popcll(m & ((1ull << lane) - 1ull));
      if (hv != 0.f && pos < 128) cbuf[wv][pos] = (unsigned short)r;
      count += __popcll(m);
    }
    if (lane == 0) csh[wv] = count;
    __syncthreads();
    int base = 0;
    #pragma unroll
    for (int u = 0; u < 4; ++u) base += (u < wv) ? csh[u] : 0;
    int total = csh[0] + csh[1] + csh[2] + csh[3];
    int cc = min(count, 128);
    for (int i = lane; i < cc; i += 64) {
      int p = base + i;
      if (p < 192) clist[e * 192 + p] = cbuf[wv][i];
    }
    if (t == 0) {
      ccnt[e] = total;
      de[e] = total ? 1.f / (float)total : 0.f;
    }
  } else if (bid < 1536) {
    // ---- rfill (coalesced row scans), 4 rows per block
    int n = (bid - 1024) * 4 + wv;
    const float* row = H + (size_t)n * EE;
    int count = 0;
    for (int i = 0; i < EE; i += 64) {
      float hv = row[i + lane];
      ull m = __ballot(hv != 0.f);
      int pos = count + __popcll(m & ((1ull << lane) - 1ull));
      if (hv != 0.f && pos < 128) elist[n * 128 + pos] = (unsigned short)(i + lane);
      count += __popcll(m);
    }
    if (lane == 0) {
      cnt[n] = count;
      dn[n] = count ? rsqrtf((float)count) : 0.f;
    }
  } else {
    // ---- npb: 8 rows x 128 h per block; W1 node-half transposed in LDS
    float* Wt = smem;
    float* xl = smem + 64 * 129;
    int b = bid - 1536;
    int r0 = b * 8;
    #pragma unroll
    for (int p = 0; p < 32; ++p) {
      int j = t + p * 256;
      int h = j >> 6, d = j & 63;
      Wt[d * 129 + h] = W1[h * 128 + d];
    }
    {
      int r = t >> 6, d = t & 63;
      xl[(r + 0) * 64 + d] = x[(size_t)(r0 + r) * 64 + d];
      xl[(r + 4) * 64 + d] = x[(size_t)(r0 + r + 4) * 64 + d];
    }
    __syncthreads();
    #pragma unroll
    for (int k = 0; k < 4; ++k) {
      int idx = t + k * 256;
      int row = idx >> 7, h = idx & 127;
      float acc = b1[h];
      #pragma unroll 8
      for (int d = 0; d < 64; ++d)
        acc += xl[row * 64 + d] * Wt[d * 129 + h];
      npb[(size_t)(r0 + row) * 128 + h] = acc;
    }
  }
}

// ---------------------------------------------------------------------------
// D2 k_edge (grid EE, block per edge): FUSED ef-gather + edge projection +
// column-pass scores + w reduction.  Column scores only need THIS edge's epb,
// so everything stays block-local; epb also written out for D3's row pass.
//   ef[d]   = sum_{n in col(e)} x[n][d]                (4-wave strided)
//   epb[e]  = ef @ W1[:,64:128]^T                      (LDS-staged Wt)
//   w[e][d] = de[e] * sum_j sigmoid(score(n_j,e)) * dn[n_j] * x[n_j][d]
// ---------------------------------------------------------------------------
__global__ void k_edge(const unsigned short* __restrict__ clist,
                       const int* __restrict__ ccnt, const float* __restrict__ de,
                       const float* __restrict__ dn, const float* __restrict__ x,
                       const float* __restrict__ W1, const float* __restrict__ npb,
                       const float* __restrict__ W2, const float* __restrict__ b2,
                       float* __restrict__ epb, float* __restrict__ w) {
  __shared__ __align__(16) float Wt[64 * 129];
  __shared__ float psum[4][64];
  __shared__ float efl[64];
  __shared__ float epl[128];
  __shared__ float pp[2][128];
  int t = threadIdx.x, wv = t >> 6, lane = t & 63;
  int e = blockIdx.x;
  #pragma unroll
  for (int p = 0; p < 32; ++p) {
    int j = t + p * 256;
    int h = j >> 6, d = j & 63;
    Wt[d * 129 + h] = W1[h * 128 + 64 + d];
  }
  int c = min(ccnt[e], 192);
  // pass 1: ef gather (wave-strided entries, coalesced x rows)
  float acc = 0.f;
  for (int j = wv; j < c; j += 4) {
    int n = clist[e * 192 + j];
    acc += x[(size_t)n * 64 + lane];
  }
  psum[wv][lane] = acc;
  __syncthreads();
  if (wv == 0)
    efl[lane] = psum[0][lane] + psum[1][lane] + psum[2][lane] + psum[3][lane];
  __syncthreads();
  // projection: 256 threads cover 128 h x 2 d-halves
  {
    int h = t & 127, half = t >> 7;
    float a = 0.f;
    #pragma unroll 8
    for (int d = half * 32; d < half * 32 + 32; ++d)
      a += efl[d] * Wt[d * 129 + h];
    pp[half][h] = a;
  }
  __syncthreads();
  if (t < 128) {
    float v = pp[0][t] + pp[1][t];
    epl[t] = v;
    epb[(size_t)e * 128 + t] = v;
  }
  __syncthreads();
  // pass 2: per-entry score + weighted gather (ep, W2 in registers)
  float epa = epl[lane], epc = epl[64 + lane];
  float w2a = W2[lane], w2b = W2[64 + lane];
  float b2v = b2[0];
  float accw = 0.f;
  for (int j = wv; j < c; j += 4) {
    int n = clist[e * 192 + j];
    float sc = fmaxf(npb[(size_t)n * 128 + lane] + epa, 0.f) * w2a
             + fmaxf(npb[(size_t)n * 128 + 64 + lane] + epc, 0.f) * w2b;
    #pragma unroll
    for (int o = 32; o > 0; o >>= 1) sc += __shfl_xor(sc, o, 64);
    float s = dn[n] / (1.f + __expf(-(sc + b2v)));
    accw += s * x[(size_t)n * 64 + lane];
  }
  __syncthreads();
  psum[wv][lane] = accw;
  __syncthreads();
  if (wv == 0)
    w[(size_t)e * 64 + lane] =
        de[e] * (psum[0][lane] + psum[1][lane] + psum[2][lane] + psum[3][lane]);
}

// ---------------------------------------------------------------------------
// D3 k_node (grid NN, block per node): FUSED row-pass scores + z gather +
// final linear.  np[n] staged in LDS/regs; ep[e_j] and w[e_j] streamed.
//   z[d]  = dn[n] * sum_j sigmoid(score(n,e_j)) * w[e_j][d]
//   out[n][o] = z . Wl[o] + bl[o]
// ---------------------------------------------------------------------------
__global__ void k_node(const unsigned short* __restrict__ elist, const int* __restrict__ cnt,
                       const float* __restrict__ dn, const float* __restrict__ npb,
                       const float* __restrict__ epb, const float* __restrict__ W2,
                       const float* __restrict__ b2, const float* __restrict__ w,
                       const float* __restrict__ Wlg, const float* __restrict__ bl,
                       float* __restrict__ out) {
  __shared__ __align__(16) float Wlds[64 * 65];
  __shared__ float npl[128];
  __shared__ float psum[4][64];
  __shared__ float zl[64];
  int t = threadIdx.x, wv = t >> 6, lane = t & 63;
  int n = blockIdx.x;
  #pragma unroll
  for (int p = 0; p < 16; ++p) {
    int j = t + p * 256;
    Wlds[(j >> 6) * 65 + (j & 63)] = Wlg[j];
  }
  if (t < 128) npl[t] = npb[(size_t)n * 128 + t];
  __syncthreads();
  float npa = npl[lane], npc = npl[64 + lane];
  float w2a = W2[lane], w2b = W2[64 + lane];
  float b2v = b2[0];
  int c = min(cnt[n], 128);
  float acc = 0.f;
  for (int j = wv; j < c; j += 4) {
    int e = elist[n * 128 + j];
    float sc = fmaxf(npa + epb[(size_t)e * 128 + lane], 0.f) * w2a
             + fmaxf(npc + epb[(size_t)e * 128 + 64 + lane], 0.f) * w2b;
    #pragma unroll
    for (int o = 32; o > 0; o >>= 1) sc += __shfl_xor(sc, o, 64);
    float s = 1.f / (1.f + __expf(-(sc + b2v)));
    acc += s * w[(size_t)e * 64 + lane];
  }
  psum[wv][lane] = acc;
  __syncthreads();
  if (wv == 0)
    zl[lane] = dn[n] * (psum[0][lane] + psum[1][lane] + psum[2][lane] + psum[3][lane]);
  __syncthreads();
  // final linear: o = lane, quarter wv covers d in [wv*16, wv*16+16)
  {
    float po = 0.f;
    #pragma unroll
    for (int d = wv * 16; d < wv * 16 + 16; ++d)
      po += zl[d] * Wlds[lane * 65 + d];
    psum[wv][lane] = po;
  }
  __syncthreads();
  if (wv == 0)
    out[(size_t)n * 64 + lane] =
        bl[lane] + psum[0][lane] + psum[1][lane] + psum[2][lane] + psum[3][lane];
}

extern "C" void kernel_launch(void* const* d_in, const int* in_sizes, int n_in,
                              void* d_out, int out_size, void* d_ws, size_t ws_size,
                              hipStream_t stream) {
  const float* x  = (const float*)d_in[0];
  const float* H  = (const float*)d_in[1];
  const float* W1 = (const float*)d_in[2];
  const float* b1 = (const float*)d_in[3];
  const float* W2 = (const float*)d_in[4];
  const float* b2 = (const float*)d_in[5];
  const float* Wl = (const float*)d_in[6];
  const float* bl = (const float*)d_in[7];
  float* out = (float*)d_out;

  char* wsb = (char*)d_ws;
  float* dn   = (float*)wsb;  wsb += NN * 4;
  float* de   = (float*)wsb;  wsb += EE * 4;
  int*   cnt  = (int*)wsb;    wsb += NN * 4;
  int*   ccnt = (int*)wsb;    wsb += EE * 4;
  float* npb  = (float*)wsb;  wsb += (size_t)NN * 128 * 4;
  float* epb  = (float*)wsb;  wsb += (size_t)EE * 128 * 4;
  float* w    = (float*)wsb;  wsb += (size_t)EE * 64 * 4;
  unsigned short* elist = (unsigned short*)wsb; wsb += (size_t)NN * 128 * 2;
  unsigned short* clist = (unsigned short*)wsb; wsb += (size_t)EE * 192 * 2;

  // D1: sparsity structure + degrees + node projection
  hipLaunchKernelGGL(k_scan, dim3(1792), dim3(256), 0, stream,
                     H, x, W1, b1, elist, cnt, dn, clist, ccnt, de, npb);
  // D2: ef + edge projection + column scores + w   (block per edge)
  hipLaunchKernelGGL(k_edge, dim3(EE), dim3(256), 0, stream,
                     clist, ccnt, de, dn, x, W1, npb, W2, b2, epb, w);
  // D3: row scores + z + final linear              (block per node)
  hipLaunchKernelGGL(k_node, dim3(NN), dim3(256), 0, stream,
                     elist, cnt, dn, npb, epb, W2, b2, w, Wl, bl, out);
}